// Round 10
// baseline (142.140 us; speedup 1.0000x reference)
//
#include <hip/hip_runtime.h>

#define HW1 16384   // 128*128
#define HW2 4096    // 64*64
#define HW3 1024    // 32*32
#define NCH 256

typedef float f4 __attribute__((ext_vector_type(4)));

// sum of 8 channel-group partials, fixed order (deterministic)
__device__ inline float psum8(const float* __restrict__ P, int stride, int idx) {
    float s = 0.f;
    #pragma unroll
    for (int g = 0; g < 8; ++g) s += P[(size_t)g * stride + idx];
    return s;
}

// clamp-to-edge half-pixel bilinear on channel-group partial maps
__device__ inline float bilp(const float* __restrict__ P, int stride, int n,
                             int y, int x, float scl, float off) {
    float fy = y * scl - off, fx = x * scl - off;
    float fy0 = floorf(fy), fx0 = floorf(fx);
    float wy = fy - fy0, wx = fx - fx0;
    int y0 = max((int)fy0, 0), y1 = min((int)fy0 + 1, n - 1);
    int x0 = max((int)fx0, 0), x1 = min((int)fx0 + 1, n - 1);
    float m00 = psum8(P, stride, y0 * n + x0), m01 = psum8(P, stride, y0 * n + x1);
    float m10 = psum8(P, stride, y1 * n + x0), m11 = psum8(P, stride, y1 * n + x1);
    float a = m00 * (1.f - wx) + m01 * wx;
    float b = m10 * (1.f - wx) + m11 * wx;
    return a * (1.f - wy) + b * wy;
}

// Contiguous-read channel-group sums (identical to round 8).
__global__ __launch_bounds__(256) void k_sumsA(
    const float* __restrict__ l1, const float* __restrict__ l2, const float* __restrict__ l3,
    float* __restrict__ P1, float* __restrict__ P2, float* __restrict__ P3) {
    int t = threadIdx.x, blk = blockIdx.x;
    const float* src; float* dst; int hw, px0, b, cg;
    if (blk < 512) {
        b = blk >> 7; cg = (blk >> 4) & 7; int q = blk & 15;
        hw = HW1; src = l1; dst = P1; px0 = q * 1024;
    } else if (blk < 640) {
        int k = blk - 512; b = k >> 5; cg = (k >> 2) & 7; int q = k & 3;
        hw = HW2; src = l2; dst = P2; px0 = q * 1024;
    } else {
        int k = blk - 640; b = k >> 3; cg = k & 7;
        hw = HW3; src = l3; dst = P3; px0 = 0;
    }
    const f4* s = (const f4*)(src + ((size_t)(b * NCH + cg * 32)) * hw + px0);
    int hw4 = hw >> 2;
    f4 acc = {0.f, 0.f, 0.f, 0.f};
    #pragma unroll 8
    for (int c = 0; c < 32; ++c)
        acc += s[(size_t)c * hw4 + t];
    ((f4*)(dst + ((size_t)(b * 8 + cg)) * hw + px0))[t] = acc;
}

// k_query v3: 32 blocks x 8 rows. Weights read once per block (8x reuse),
// 8-way ILP accumulators.
__global__ __launch_bounds__(256) void k_query(
    const float* __restrict__ P1, const float* __restrict__ P2, const float* __restrict__ P3,
    const float* __restrict__ qb,
    const float* __restrict__ ow1, const float* __restrict__ ob1,
    const float* __restrict__ ow2, const float* __restrict__ ob2,
    const float* __restrict__ sw1, const float* __restrict__ sb1,
    const float* __restrict__ sw2, const float* __restrict__ sb2,
    int* __restrict__ RS, int* __restrict__ CS, float* __restrict__ SC) {
    __shared__ float feat[8][256];
    __shared__ float hid[2][8][128];
    __shared__ float res[8][3];
    int t = threadIdx.x;
    int n0 = blockIdx.x * 8;

    // stage features for 8 rows (2048 values; 8 per thread)
    for (int v = t; v < 2048; v += 256) {
        int r = v >> 8, d = v & 255;
        int n = n0 + r;
        int b = n & 3, qp = n >> 2;
        int qi = qp >> 3, qj = qp & 7;
        int i = d >> 4, j = d & 15;
        int y = 16 * qi + i, x = 16 * qj + j;
        const float* P1b = P1 + (size_t)b * 8 * HW1;
        const float* P2b = P2 + (size_t)b * 8 * HW2;
        const float* P3b = P3 + (size_t)b * 8 * HW3;
        float val = psum8(P1b, HW1, y * 128 + x);
        val += bilp(P2b, HW2, 64, y, x, 0.5f, 0.25f);
        val += bilp(P3b, HW3, 32, y, x, 0.25f, 0.375f);
        feat[r][d] = val * (1.0f / 768.0f);
    }
    __syncthreads();

    // layer 1: m = matrix (0=offset,1=scale), h = hidden unit
    {
        int m = t >> 7, h = t & 127;
        const float* W  = m ? sw1 : ow1;
        float bias = (m ? sb1 : ob1)[h];
        float acc[8];
        #pragma unroll
        for (int r = 0; r < 8; ++r) acc[r] = 0.f;
        for (int d = 0; d < 256; ++d) {
            float w = W[d * 128 + h];
            #pragma unroll
            for (int r = 0; r < 8; ++r)
                acc[r] = fmaf(feat[r][d], w, acc[r]);
        }
        #pragma unroll
        for (int r = 0; r < 8; ++r)
            hid[m][r][h] = fmaxf(acc[r] + bias, 0.f);
    }
    __syncthreads();

    // layer 2: 8 rows x 3 outputs = 24 serial 128-dots
    if (t < 24) {
        int r = t / 3, o = t - r * 3;
        float acc = 0.f;
        if (o == 0)      { for (int j = 0; j < 128; ++j) acc = fmaf(hid[0][r][j], ow2[2 * j],     acc); acc += ob2[0]; }
        else if (o == 1) { for (int j = 0; j < 128; ++j) acc = fmaf(hid[0][r][j], ow2[2 * j + 1], acc); acc += ob2[1]; }
        else             { for (int j = 0; j < 128; ++j) acc = fmaf(hid[1][r][j], sw2[j],         acc); acc += sb2[0]; }
        res[r][o] = acc;
    }
    __syncthreads();

    if (t < 8) {
        int n = n0 + t, q = n & 63;
        int cpx = (int)(qb[2 * q + 0] * 128.0f);
        int cpy = (int)(qb[2 * q + 1] * 128.0f);
        int cpsx = (int)((float)cpx + res[t][0] * 8.0f);
        int cpsy = (int)((float)cpy + res[t][1] * 8.0f);
        RS[n] = cpsx - 8;
        CS[n] = cpsy - 8;
        SC[n] = res[t][2];
    }
}

__global__ __launch_bounds__(256) void k_scalemap(
    const int* __restrict__ RS, const int* __restrict__ CS, const float* __restrict__ SC,
    float* __restrict__ SMAP) {
    __shared__ int rs[64], cs[64];
    __shared__ float sc[64];
    int t = threadIdx.x;
    int p = blockIdx.x * 256 + t;
    int b = p >> 14;
    if (t < 64) { rs[t] = RS[b * 64 + t]; cs[t] = CS[b * 64 + t]; sc[t] = SC[b * 64 + t]; }
    __syncthreads();
    int off = p & (HW1 - 1);
    int r = off >> 7, c = off & 127;
    float sv = 1.0f;
    for (int q = 63; q >= 0; --q) {
        int r0 = rs[q], c0 = cs[q];
        if (r0 >= 0 && c0 >= 0 && (unsigned)(r - r0) < 16u && (unsigned)(c - c0) < 16u) {
            sv = sc[q]; break;
        }
    }
    SMAP[p] = sv;
}

// Direct-channel streaming kernel: plain loads + plain stores (NT removed).
__global__ __launch_bounds__(256) void k_direct(
    const float* __restrict__ a1, const float* __restrict__ n1,
    const float* __restrict__ SMAP, float* __restrict__ out) {
    int t = threadIdx.x;
    int plane = blockIdx.x >> 1;
    int half  = blockIdx.x & 1;
    int b  = plane >> 8;
    int ch = plane & 255;
    const f4* f  = (const f4*)(a1 + ((size_t)(b * 256 + ch)) * HW1);
    const f4* fn = (const f4*)(n1 + ((size_t)(b * 256 + ch)) * HW1);
    const f4* s4 = (const f4*)(SMAP + b * HW1);
    f4* o4 = (f4*)(out + ((size_t)(b * 768 + ch)) * HW1);
    int base = half * 2048;
    #pragma unroll
    for (int k = 0; k < 8; ++k) {
        int i = base + k * 256 + t;
        f4 fv = f[i];
        f4 sv = s4[i];
        f4 nv = fn[i];
        f4 r;
        r.x = fmaf(fv.x, sv.x, nv.x);
        r.y = fmaf(fv.y, sv.y, nv.y);
        r.z = fmaf(fv.z, sv.z, nv.z);
        r.w = fmaf(fv.w, sv.w, nv.w);
        o4[i] = r;
    }
}

// Upsample-only kernel: plain loads + plain stores (NT removed).
__global__ __launch_bounds__(256, 4) void k_up(
    const float* __restrict__ a2, const float* __restrict__ a3,
    const float* __restrict__ n2, const float* __restrict__ n3,
    const float* __restrict__ SMAP, float* __restrict__ out) {
    __shared__ float cur[4096];
    __shared__ float nxt[4096];
    int t = threadIdx.x;
    int c_local = blockIdx.x >> 2;
    int b = blockIdx.x & 3;
    const f4* s4 = (const f4*)(SMAP + b * HW1);
    const size_t obase = (size_t)(b * 768) * HW1;

    {
        const f4* s0 = (const f4*)(a2 + ((size_t)(b * 256 + c_local)) * HW2);
        const f4* s1 = (const f4*)(n2 + ((size_t)(b * 256 + c_local)) * HW2);
        f4* o4 = (f4*)(out + obase + (size_t)(256 + c_local) * HW1);
        for (int i = t; i < 1024; i += 256) {
            ((f4*)cur)[i] = s0[i];
            ((f4*)nxt)[i] = s1[i];
        }
        __syncthreads();
        for (int i = t; i < 4096; i += 256) {
            int y = i >> 5, j = i & 31;
            int iy = (y - 1) >> 1;
            int y0 = max(iy, 0), y1 = min(iy + 1, 63);
            float wy = (y & 1) ? 0.25f : 0.75f;
            int cm1 = max(2 * j - 1, 0);
            int c0 = 2 * j, c1 = 2 * j + 1;
            int c2c = min(2 * j + 2, 63);
            const float* r0 = cur + y0 * 64; const float* r1 = cur + y1 * 64;
            const float* u0 = nxt + y0 * 64; const float* u1 = nxt + y1 * 64;
            float a0 = r0[cm1], a1v = r0[c0], a2v = r0[c1], a3v = r0[c2c];
            float b0 = r1[cm1], b1v = r1[c0], b2v = r1[c1], b3v = r1[c2c];
            float p0 = u0[cm1], p1 = u0[c0], p2 = u0[c1], p3 = u0[c2c];
            float q0 = u1[cm1], q1 = u1[c0], q2 = u1[c1], q3 = u1[c2c];
            float h0 = fmaf(0.25f, a0, 0.75f * a1v);
            float h1 = fmaf(0.75f, a1v, 0.25f * a2v);
            float h2 = fmaf(0.25f, a1v, 0.75f * a2v);
            float h3 = fmaf(0.75f, a2v, 0.25f * a3v);
            float g0 = fmaf(0.25f, b0, 0.75f * b1v);
            float g1 = fmaf(0.75f, b1v, 0.25f * b2v);
            float g2 = fmaf(0.25f, b1v, 0.75f * b2v);
            float g3 = fmaf(0.75f, b2v, 0.25f * b3v);
            float e0 = fmaf(0.25f, p0, 0.75f * p1);
            float e1 = fmaf(0.75f, p1, 0.25f * p2);
            float e2 = fmaf(0.25f, p1, 0.75f * p2);
            float e3 = fmaf(0.75f, p2, 0.25f * p3);
            float k0 = fmaf(0.25f, q0, 0.75f * q1);
            float k1 = fmaf(0.75f, q1, 0.25f * q2);
            float k2 = fmaf(0.25f, q1, 0.75f * q2);
            float k3 = fmaf(0.75f, q2, 0.25f * q3);
            f4 sv = s4[i];
            f4 r;
            r.x = fmaf(fmaf(g0 - h0, wy, h0), sv.x, fmaf(k0 - e0, wy, e0));
            r.y = fmaf(fmaf(g1 - h1, wy, h1), sv.y, fmaf(k1 - e1, wy, e1));
            r.z = fmaf(fmaf(g2 - h2, wy, h2), sv.z, fmaf(k2 - e2, wy, e2));
            r.w = fmaf(fmaf(g3 - h3, wy, h3), sv.w, fmaf(k3 - e3, wy, e3));
            o4[i] = r;
        }
    }

    __syncthreads();

    {
        const f4* s0 = (const f4*)(a3 + ((size_t)(b * 256 + c_local)) * HW3);
        const f4* s1 = (const f4*)(n3 + ((size_t)(b * 256 + c_local)) * HW3);
        f4* o4 = (f4*)(out + obase + (size_t)(512 + c_local) * HW1);
        for (int i = t; i < 256; i += 256) {
            ((f4*)cur)[i] = s0[i];
            ((f4*)nxt)[i] = s1[i];
        }
        __syncthreads();
        for (int i = t; i < 4096; i += 256) {
            int y = i >> 5, j = i & 31;
            int iy = (y - 2) >> 2;
            int y0 = max(iy, 0), y1 = min(iy + 1, 31);
            int ym = y & 3;
            float wy = (ym < 2) ? (0.625f + 0.25f * ym) : (0.25f * ym - 0.375f);
            int cm1 = max(j - 1, 0);
            int c0 = j, c1 = min(j + 1, 31);
            const float* r0 = cur + y0 * 32; const float* r1 = cur + y1 * 32;
            const float* u0 = nxt + y0 * 32; const float* u1 = nxt + y1 * 32;
            float a0 = r0[cm1], a1v = r0[c0], a2v = r0[c1];
            float b0 = r1[cm1], b1v = r1[c0], b2v = r1[c1];
            float p0 = u0[cm1], p1 = u0[c0], p2 = u0[c1];
            float q0 = u1[cm1], q1 = u1[c0], q2 = u1[c1];
            float h0 = fmaf(0.375f, a0, 0.625f * a1v);
            float h1 = fmaf(0.125f, a0, 0.875f * a1v);
            float h2 = fmaf(0.875f, a1v, 0.125f * a2v);
            float h3 = fmaf(0.625f, a1v, 0.375f * a2v);
            float g0 = fmaf(0.375f, b0, 0.625f * b1v);
            float g1 = fmaf(0.125f, b0, 0.875f * b1v);
            float g2 = fmaf(0.875f, b1v, 0.125f * b2v);
            float g3 = fmaf(0.625f, b1v, 0.375f * b2v);
            float e0 = fmaf(0.375f, p0, 0.625f * p1);
            float e1 = fmaf(0.125f, p0, 0.875f * p1);
            float e2 = fmaf(0.875f, p1, 0.125f * p2);
            float e3 = fmaf(0.625f, p1, 0.375f * p2);
            float k0 = fmaf(0.375f, q0, 0.625f * q1);
            float k1 = fmaf(0.125f, q0, 0.875f * q1);
            float k2 = fmaf(0.875f, q1, 0.125f * q2);
            float k3 = fmaf(0.625f, q1, 0.375f * q2);
            f4 sv = s4[i];
            f4 r;
            r.x = fmaf(fmaf(g0 - h0, wy, h0), sv.x, fmaf(k0 - e0, wy, e0));
            r.y = fmaf(fmaf(g1 - h1, wy, h1), sv.y, fmaf(k1 - e1, wy, e1));
            r.z = fmaf(fmaf(g2 - h2, wy, h2), sv.z, fmaf(k2 - e2, wy, e2));
            r.w = fmaf(fmaf(g3 - h3, wy, h3), sv.w, fmaf(k3 - e3, wy, e3));
            o4[i] = r;
        }
    }
}

extern "C" void kernel_launch(void* const* d_in, const int* in_sizes, int n_in,
                              void* d_out, int out_size, void* d_ws, size_t ws_size,
                              hipStream_t stream) {
    (void)in_sizes; (void)n_in; (void)out_size; (void)ws_size;
    const float* t0_l1 = (const float*)d_in[1];
    const float* t0_l2 = (const float*)d_in[2];
    const float* t0_l3 = (const float*)d_in[3];
    const float* t1_l1 = (const float*)d_in[5];
    const float* t1_l2 = (const float*)d_in[6];
    const float* t1_l3 = (const float*)d_in[7];
    const float* qb    = (const float*)d_in[8];
    const float* ow1   = (const float*)d_in[9];
    const float* ob1   = (const float*)d_in[10];
    const float* ow2   = (const float*)d_in[11];
    const float* ob2   = (const float*)d_in[12];
    const float* sw1   = (const float*)d_in[13];
    const float* sb1   = (const float*)d_in[14];
    const float* sw2   = (const float*)d_in[15];
    const float* sb2   = (const float*)d_in[16];

    char* ws = (char*)d_ws;
    float* P1   = (float*)(ws + 0);         // 2 MB : [4][8][16384]
    float* P2   = (float*)(ws + 2097152);   // 512 KB : [4][8][4096]
    float* P3   = (float*)(ws + 2621440);   // 128 KB : [4][8][1024]
    int*   RS   = (int*)  (ws + 2752512);
    int*   CS   = (int*)  (ws + 2753536);
    float* SC   = (float*)(ws + 2754560);
    float* SMAP = (float*)(ws + 2755584);   // 256 KB
    float* out  = (float*)d_out;

    hipLaunchKernelGGL(k_sumsA, dim3(672), dim3(256), 0, stream,
                       t0_l1, t0_l2, t0_l3, P1, P2, P3);
    hipLaunchKernelGGL(k_query, dim3(32), dim3(256), 0, stream,
                       P1, P2, P3, qb, ow1, ob1, ow2, ob2, sw1, sb1, sw2, sb2, RS, CS, SC);
    hipLaunchKernelGGL(k_scalemap, dim3(256), dim3(256), 0, stream, RS, CS, SC, SMAP);
    hipLaunchKernelGGL(k_direct, dim3(2048), dim3(256), 0, stream,
                       t0_l1, t1_l1, SMAP, out);
    hipLaunchKernelGGL(k_up, dim3(1024), dim3(256), 0, stream,
                       t0_l2, t0_l3, t1_l2, t1_l3, SMAP, out);
}

// Round 11
// 103.162 us; speedup vs baseline: 1.3778x; 1.3778x over previous
//
#include <hip/hip_runtime.h>

#define HW1 16384   // 128*128
#define HW2 4096    // 64*64
#define HW3 1024    // 32*32
#define NB  4
#define NCH 256

typedef float f4 __attribute__((ext_vector_type(4)));

__device__ inline float4 f4add(float4 a, float4 b) {
    a.x += b.x; a.y += b.y; a.z += b.z; a.w += b.w; return a;
}

// clamp-to-edge half-pixel bilinear sample of an n x n map at output coord (y,x)
__device__ inline float bil(const float* m, int n, int y, int x, float scl, float off) {
    float fy = y * scl - off, fx = x * scl - off;
    float fy0 = floorf(fy), fx0 = floorf(fx);
    float wy = fy - fy0, wx = fx - fx0;
    int y0 = max((int)fy0, 0), y1 = min((int)fy0 + 1, n - 1);
    int x0 = max((int)fx0, 0), x1 = min((int)fx0 + 1, n - 1);
    float a = m[y0 * n + x0] * (1.f - wx) + m[y0 * n + x1] * wx;
    float b = m[y1 * n + x0] * (1.f - wx) + m[y1 * n + x1] * wx;
    return a * (1.f - wy) + b * wy;
}

// Channel sums of t0_l1 (128x128), t0_l2 (64x64), t0_l3 (32x32).
__global__ __launch_bounds__(256) void k_sums(
    const float* __restrict__ l1, const float* __restrict__ l2, const float* __restrict__ l3,
    float* __restrict__ SUM1, float* __restrict__ S2, float* __restrict__ S3) {
    __shared__ float4 red[256];
    int t = threadIdx.x, s = t >> 5, g = t & 31;
    int blk = blockIdx.x;
    const float* src; float* dst; int hw; int gg;
    if (blk < 512) {
        gg = blk * 32 + g; int p4 = gg * 4;
        int b = p4 >> 14, off = p4 & (HW1 - 1);
        src = l1 + ((size_t)(b * NCH + s * 32)) * HW1 + off; dst = SUM1; hw = HW1;
    } else if (blk < 640) {
        gg = (blk - 512) * 32 + g; int p4 = gg * 4;
        int b = p4 >> 12, off = p4 & (HW2 - 1);
        src = l2 + ((size_t)(b * NCH + s * 32)) * HW2 + off; dst = S2; hw = HW2;
    } else {
        gg = (blk - 640) * 32 + g; int p4 = gg * 4;
        int b = p4 >> 10, off = p4 & (HW3 - 1);
        src = l3 + ((size_t)(b * NCH + s * 32)) * HW3 + off; dst = S3; hw = HW3;
    }
    float4 acc = make_float4(0.f, 0.f, 0.f, 0.f);
    #pragma unroll 8
    for (int c = 0; c < 32; ++c)
        acc = f4add(acc, *(const float4*)(src + (size_t)c * hw));
    red[t] = acc;
    __syncthreads();
    if (s < 4) red[t] = f4add(red[t], red[t + 128]);
    __syncthreads();
    if (s < 2) red[t] = f4add(red[t], red[t + 64]);
    __syncthreads();
    if (s == 0) {
        float4 r = f4add(red[t], red[t + 32]);
        ((float4*)dst)[gg] = r;
    }
}

// One block (256 thr) per output row n = b'*64 + q'.
__global__ __launch_bounds__(256) void k_query(
    const float* __restrict__ SUM1, const float* __restrict__ S2, const float* __restrict__ S3,
    const float* __restrict__ qb,
    const float* __restrict__ ow1, const float* __restrict__ ob1,
    const float* __restrict__ ow2, const float* __restrict__ ob2,
    const float* __restrict__ sw1, const float* __restrict__ sb1,
    const float* __restrict__ sw2, const float* __restrict__ sb2,
    int* __restrict__ RS, int* __restrict__ CS, float* __restrict__ SC) {
    __shared__ float feat[256];
    __shared__ float hid[256];
    __shared__ float res[3];
    int n = blockIdx.x, t = threadIdx.x;
    int b = n & 3, qp = n >> 2;
    int qi = qp >> 3, qj = qp & 7;
    {
        int i = t >> 4, j = t & 15;
        int y = 16 * qi + i, x = 16 * qj + j;
        float v = SUM1[b * HW1 + y * 128 + x];
        v += bil(S2 + b * HW2, 64, y, x, 0.5f, 0.25f);
        v += bil(S3 + b * HW3, 32, y, x, 0.25f, 0.375f);
        feat[t] = v * (1.0f / 768.0f);
    }
    __syncthreads();
    {
        int h = t & 127;
        const float* W  = (t < 128) ? ow1 : sw1;
        const float* Bv = (t < 128) ? ob1 : sb1;
        float acc = 0.f;
        #pragma unroll 8
        for (int d = 0; d < 256; ++d)
            acc = fmaf(feat[d], W[d * 128 + h], acc);
        hid[t] = fmaxf(acc + Bv[h], 0.f);
    }
    __syncthreads();
    int w = t >> 6, l = t & 63;
    if (w < 3) {
        float acc;
        if (w == 0)      acc = fmaf(hid[l], ow2[2 * l],     hid[l + 64] * ow2[2 * l + 128]);
        else if (w == 1) acc = fmaf(hid[l], ow2[2 * l + 1], hid[l + 64] * ow2[2 * l + 129]);
        else             acc = fmaf(hid[128 + l], sw2[l],   hid[192 + l] * sw2[l + 64]);
        #pragma unroll
        for (int off = 32; off; off >>= 1) acc += __shfl_down(acc, off);
        if (l == 0) res[w] = acc + (w == 0 ? ob2[0] : (w == 1 ? ob2[1] : sb2[0]));
    }
    __syncthreads();
    if (t == 0) {
        int q = n & 63;
        int cpx = (int)(qb[2 * q + 0] * 128.0f);
        int cpy = (int)(qb[2 * q + 1] * 128.0f);
        int cpsx = (int)((float)cpx + res[0] * 8.0f);
        int cpsy = (int)((float)cpy + res[1] * 8.0f);
        RS[n] = cpsx - 8;
        CS[n] = cpsy - 8;
        SC[n] = res[2];
    }
}

__global__ __launch_bounds__(256) void k_scalemap(
    const int* __restrict__ RS, const int* __restrict__ CS, const float* __restrict__ SC,
    float* __restrict__ SMAP) {
    __shared__ int rs[64], cs[64];
    __shared__ float sc[64];
    int t = threadIdx.x;
    int p = blockIdx.x * 256 + t;
    int b = p >> 14;
    if (t < 64) { rs[t] = RS[b * 64 + t]; cs[t] = CS[b * 64 + t]; sc[t] = SC[b * 64 + t]; }
    __syncthreads();
    int off = p & (HW1 - 1);
    int r = off >> 7, c = off & 127;
    float sv = 1.0f;
    for (int q = 63; q >= 0; --q) {
        int r0 = rs[q], c0 = cs[q];
        if (r0 >= 0 && c0 >= 0 && (unsigned)(r - r0) < 16u && (unsigned)(c - c0) < 16u) {
            sv = sc[q]; break;
        }
    }
    SMAP[p] = sv;
}

// Upsample-only kernel: 1024 blocks, each does one 2x plane + one 4x plane
// sharing (c_local, b). NT loads on t1, NT stores on out (R6 config).
__global__ __launch_bounds__(256, 4) void k_up(
    const float* __restrict__ a2, const float* __restrict__ a3,
    const float* __restrict__ n2, const float* __restrict__ n3,
    const float* __restrict__ SMAP, float* __restrict__ out) {
    __shared__ float cur[4096];
    __shared__ float nxt[4096];
    int t = threadIdx.x;
    int c_local = blockIdx.x >> 2;
    int b = blockIdx.x & 3;
    const f4* s4 = (const f4*)(SMAP + b * HW1);
    const size_t obase = (size_t)(b * 768) * HW1;

    // ---- 2x upsample channel 256 + c_local ----
    {
        const f4* s0 = (const f4*)(a2 + ((size_t)(b * 256 + c_local)) * HW2);
        const f4* s1 = (const f4*)(n2 + ((size_t)(b * 256 + c_local)) * HW2);
        f4* o4 = (f4*)(out + obase + (size_t)(256 + c_local) * HW1);
        for (int i = t; i < 1024; i += 256) {
            ((f4*)cur)[i] = s0[i];
            ((f4*)nxt)[i] = __builtin_nontemporal_load(&s1[i]);
        }
        __syncthreads();
        for (int i = t; i < 4096; i += 256) {
            int y = i >> 5, j = i & 31;
            int iy = (y - 1) >> 1;
            int y0 = max(iy, 0), y1 = min(iy + 1, 63);
            float wy = (y & 1) ? 0.25f : 0.75f;
            int cm1 = max(2 * j - 1, 0);
            int c0 = 2 * j, c1 = 2 * j + 1;
            int c2c = min(2 * j + 2, 63);
            const float* r0 = cur + y0 * 64; const float* r1 = cur + y1 * 64;
            const float* u0 = nxt + y0 * 64; const float* u1 = nxt + y1 * 64;
            float a0 = r0[cm1], a1v = r0[c0], a2v = r0[c1], a3v = r0[c2c];
            float b0 = r1[cm1], b1v = r1[c0], b2v = r1[c1], b3v = r1[c2c];
            float p0 = u0[cm1], p1 = u0[c0], p2 = u0[c1], p3 = u0[c2c];
            float q0 = u1[cm1], q1 = u1[c0], q2 = u1[c1], q3 = u1[c2c];
            float h0 = fmaf(0.25f, a0, 0.75f * a1v);
            float h1 = fmaf(0.75f, a1v, 0.25f * a2v);
            float h2 = fmaf(0.25f, a1v, 0.75f * a2v);
            float h3 = fmaf(0.75f, a2v, 0.25f * a3v);
            float g0 = fmaf(0.25f, b0, 0.75f * b1v);
            float g1 = fmaf(0.75f, b1v, 0.25f * b2v);
            float g2 = fmaf(0.25f, b1v, 0.75f * b2v);
            float g3 = fmaf(0.75f, b2v, 0.25f * b3v);
            float e0 = fmaf(0.25f, p0, 0.75f * p1);
            float e1 = fmaf(0.75f, p1, 0.25f * p2);
            float e2 = fmaf(0.25f, p1, 0.75f * p2);
            float e3 = fmaf(0.75f, p2, 0.25f * p3);
            float k0 = fmaf(0.25f, q0, 0.75f * q1);
            float k1 = fmaf(0.75f, q1, 0.25f * q2);
            float k2 = fmaf(0.25f, q1, 0.75f * q2);
            float k3 = fmaf(0.75f, q2, 0.25f * q3);
            f4 sv = s4[i];
            f4 r;
            r.x = fmaf(fmaf(g0 - h0, wy, h0), sv.x, fmaf(k0 - e0, wy, e0));
            r.y = fmaf(fmaf(g1 - h1, wy, h1), sv.y, fmaf(k1 - e1, wy, e1));
            r.z = fmaf(fmaf(g2 - h2, wy, h2), sv.z, fmaf(k2 - e2, wy, e2));
            r.w = fmaf(fmaf(g3 - h3, wy, h3), sv.w, fmaf(k3 - e3, wy, e3));
            __builtin_nontemporal_store(r, &o4[i]);
        }
    }

    __syncthreads();   // all reads of cur/nxt done before restage

    // ---- 4x upsample channel 512 + c_local ----
    {
        const f4* s0 = (const f4*)(a3 + ((size_t)(b * 256 + c_local)) * HW3);
        const f4* s1 = (const f4*)(n3 + ((size_t)(b * 256 + c_local)) * HW3);
        f4* o4 = (f4*)(out + obase + (size_t)(512 + c_local) * HW1);
        for (int i = t; i < 256; i += 256) {
            ((f4*)cur)[i] = s0[i];
            ((f4*)nxt)[i] = __builtin_nontemporal_load(&s1[i]);
        }
        __syncthreads();
        for (int i = t; i < 4096; i += 256) {
            int y = i >> 5, j = i & 31;
            int iy = (y - 2) >> 2;
            int y0 = max(iy, 0), y1 = min(iy + 1, 31);
            int ym = y & 3;
            float wy = (ym < 2) ? (0.625f + 0.25f * ym) : (0.25f * ym - 0.375f);
            int cm1 = max(j - 1, 0);
            int c0 = j, c1 = min(j + 1, 31);
            const float* r0 = cur + y0 * 32; const float* r1 = cur + y1 * 32;
            const float* u0 = nxt + y0 * 32; const float* u1 = nxt + y1 * 32;
            float a0 = r0[cm1], a1v = r0[c0], a2v = r0[c1];
            float b0 = r1[cm1], b1v = r1[c0], b2v = r1[c1];
            float p0 = u0[cm1], p1 = u0[c0], p2 = u0[c1];
            float q0 = u1[cm1], q1 = u1[c0], q2 = u1[c1];
            float h0 = fmaf(0.375f, a0, 0.625f * a1v);
            float h1 = fmaf(0.125f, a0, 0.875f * a1v);
            float h2 = fmaf(0.875f, a1v, 0.125f * a2v);
            float h3 = fmaf(0.625f, a1v, 0.375f * a2v);
            float g0 = fmaf(0.375f, b0, 0.625f * b1v);
            float g1 = fmaf(0.125f, b0, 0.875f * b1v);
            float g2 = fmaf(0.875f, b1v, 0.125f * b2v);
            float g3 = fmaf(0.625f, b1v, 0.375f * b2v);
            float e0 = fmaf(0.375f, p0, 0.625f * p1);
            float e1 = fmaf(0.125f, p0, 0.875f * p1);
            float e2 = fmaf(0.875f, p1, 0.125f * p2);
            float e3 = fmaf(0.625f, p1, 0.375f * p2);
            float k0 = fmaf(0.375f, q0, 0.625f * q1);
            float k1 = fmaf(0.125f, q0, 0.875f * q1);
            float k2 = fmaf(0.875f, q1, 0.125f * q2);
            float k3 = fmaf(0.625f, q1, 0.375f * q2);
            f4 sv = s4[i];
            f4 r;
            r.x = fmaf(fmaf(g0 - h0, wy, h0), sv.x, fmaf(k0 - e0, wy, e0));
            r.y = fmaf(fmaf(g1 - h1, wy, h1), sv.y, fmaf(k1 - e1, wy, e1));
            r.z = fmaf(fmaf(g2 - h2, wy, h2), sv.z, fmaf(k2 - e2, wy, e2));
            r.w = fmaf(fmaf(g3 - h3, wy, h3), sv.w, fmaf(k3 - e3, wy, e3));
            __builtin_nontemporal_store(r, &o4[i]);
        }
    }
}

// Direct-channel streaming kernel: 2048 blocks x 256 thr, half a plane each.
// NT loads on t1, NT stores on out (R6 config).
__global__ __launch_bounds__(256) void k_direct(
    const float* __restrict__ a1, const float* __restrict__ n1,
    const float* __restrict__ SMAP, float* __restrict__ out) {
    int t = threadIdx.x;
    int plane = blockIdx.x >> 1;
    int half  = blockIdx.x & 1;
    int b  = plane >> 8;
    int ch = plane & 255;
    const f4* f  = (const f4*)(a1 + ((size_t)(b * 256 + ch)) * HW1);
    const f4* fn = (const f4*)(n1 + ((size_t)(b * 256 + ch)) * HW1);
    const f4* s4 = (const f4*)(SMAP + b * HW1);
    f4* o4 = (f4*)(out + ((size_t)(b * 768 + ch)) * HW1);
    int base = half * 2048;
    #pragma unroll
    for (int k = 0; k < 8; ++k) {
        int i = base + k * 256 + t;
        f4 fv = f[i];
        f4 sv = s4[i];
        f4 nv = __builtin_nontemporal_load(&fn[i]);
        f4 r;
        r.x = fmaf(fv.x, sv.x, nv.x);
        r.y = fmaf(fv.y, sv.y, nv.y);
        r.z = fmaf(fv.z, sv.z, nv.z);
        r.w = fmaf(fv.w, sv.w, nv.w);
        __builtin_nontemporal_store(r, &o4[i]);
    }
}

extern "C" void kernel_launch(void* const* d_in, const int* in_sizes, int n_in,
                              void* d_out, int out_size, void* d_ws, size_t ws_size,
                              hipStream_t stream) {
    (void)in_sizes; (void)n_in; (void)out_size; (void)ws_size;
    const float* t0_l1 = (const float*)d_in[1];
    const float* t0_l2 = (const float*)d_in[2];
    const float* t0_l3 = (const float*)d_in[3];
    const float* t1_l1 = (const float*)d_in[5];
    const float* t1_l2 = (const float*)d_in[6];
    const float* t1_l3 = (const float*)d_in[7];
    const float* qb    = (const float*)d_in[8];
    const float* ow1   = (const float*)d_in[9];
    const float* ob1   = (const float*)d_in[10];
    const float* ow2   = (const float*)d_in[11];
    const float* ob2   = (const float*)d_in[12];
    const float* sw1   = (const float*)d_in[13];
    const float* sb1   = (const float*)d_in[14];
    const float* sw2   = (const float*)d_in[15];
    const float* sb2   = (const float*)d_in[16];

    char* ws = (char*)d_ws;
    float* SUM1 = (float*)(ws + 0);
    float* S2   = (float*)(ws + 262144);
    float* S3   = (float*)(ws + 327680);
    int*   RS   = (int*)  (ws + 344064);
    int*   CS   = (int*)  (ws + 345088);
    float* SC   = (float*)(ws + 346112);
    float* SMAP = (float*)(ws + 347136);
    float* out  = (float*)d_out;

    hipLaunchKernelGGL(k_sums, dim3(672), dim3(256), 0, stream,
                       t0_l1, t0_l2, t0_l3, SUM1, S2, S3);
    hipLaunchKernelGGL(k_query, dim3(256), dim3(256), 0, stream,
                       SUM1, S2, S3, qb, ow1, ob1, ow2, ob2, sw1, sb1, sw2, sb2, RS, CS, SC);
    hipLaunchKernelGGL(k_scalemap, dim3(256), dim3(256), 0, stream, RS, CS, SC, SMAP);
    hipLaunchKernelGGL(k_up, dim3(1024), dim3(256), 0, stream,
                       t0_l2, t0_l3, t1_l2, t1_l3, SMAP, out);
    hipLaunchKernelGGL(k_direct, dim3(2048), dim3(256), 0, stream,
                       t0_l1, t1_l1, SMAP, out);
}